// Round 8
// baseline (111.540 us; speedup 1.0000x reference)
//
#include <hip/hip_runtime.h>
#include <hip/hip_bf16.h>

using f32x4 = __attribute__((ext_vector_type(4))) float;
using s16x8 = __attribute__((ext_vector_type(8))) short;
using u32x4 = __attribute__((ext_vector_type(4))) unsigned;

// Problem dims (fixed by reference setup_inputs)
constexpr int Bn = 4, Cc = 32, Hh = 256, Ww = 256;
constexpr int H2 = 128, W2 = 128;
constexpr int NF = 128;                 // KAN feature dim (= W2)
constexpr long NROWS = (long)Bn * Cc * 4 * H2;  // 65536 KAN rows
constexpr int KTOT = 1152;              // 128 features x 9 (silu + 8 bases)
constexpr int KCH = 288;                // K-chunk: 32 features x 9

// ---- bf16 round-to-nearest-even ----
__device__ __forceinline__ short f2bf(float f) {
    union { float f; unsigned u; } v; v.f = f;
    unsigned r = v.u + 0x7fffu + ((v.u >> 16) & 1u);
    return (short)(r >> 16);
}

// hardware bf16 pair pack (v_cvt_pk_bf16_f32)
__device__ __forceinline__ unsigned pk_bf16(float a, float b) {
    union { __hip_bfloat162 h; unsigned u; } c;
    c.h.x = __float2bfloat16(a);
    c.h.y = __float2bfloat16(b);
    return c.u;
}

// Place [wD,wC,wB,wA] (bf16-packed u64) at slot (ci-3) of an 8-slot 128-bit
// window; slots outside [0,7] dropped. ci guaranteed in [0,10] by caller.
__device__ __forceinline__ void window128(float wD, float wC, float wB, float wA,
                                          int ci, unsigned W[4]) {
    unsigned long long P = ((unsigned long long)pk_bf16(wB, wA) << 32)
                         | (unsigned long long)pk_bf16(wD, wC);
    int sh = ci * 16 - 48;
    unsigned long long sl = P << (sh & 63);
    unsigned long long sr = P >> ((-sh) & 63);
    unsigned long long lo = (sh < 0) ? sr : ((sh < 64) ? sl : 0ull);
    int shh = sh - 64;
    unsigned long long sl2 = P << (shh & 63);
    unsigned long long sr2 = P >> ((-shh) & 63);
    unsigned long long hi = (shh >= 0) ? sl2 : (((-shh) < 64) ? sr2 : 0ull);
    W[0] = (unsigned)lo; W[1] = (unsigned)(lo >> 32);
    W[2] = (unsigned)hi; W[3] = (unsigned)(hi >> 32);
}

// ---- KW: fused bf16 weight matrix Bg[o][k], k = jg*288 + g*32 + jl ----
__global__ __launch_bounds__(256) void k_wbuild(const float* __restrict__ base_w,
                                                const float* __restrict__ spline_w,
                                                const float* __restrict__ scaler,
                                                short* __restrict__ Bg) {
    int idx = blockIdx.x * 256 + threadIdx.x;
    int o = idx / KTOT;
    int k = idx - o * KTOT;
    int jg = k / KCH; int rem = k - jg * KCH;
    int g = rem >> 5; int jl = rem & 31;
    int j = jg * 32 + jl;
    float v = (g == 0) ? base_w[o * NF + j]
                       : spline_w[(long)(o * NF + j) * 8 + (g - 1)] * scaler[o * NF + j];
    Bg[idx] = f2bf(v);
}

// ---- K3: register-fragment KAN, split-K across wave pairs ----
// chunk = 16 i-rows x 4 kcomp x 128 cols; 2 waves/chunk (jg 0-1 / 2-3).
// 2048 waves = 2/SIMD. LDS only for the final partial-acc reduce.
__global__ __launch_bounds__(256, 2) void k_fused(const float* __restrict__ x,
                                                  float* __restrict__ z,
                                                  const short* __restrict__ Bg) {
    __shared__ float red[2][128][64];           // 64 KB: [chunk][mi*32+ni*4+rr][lane]
    const int t = threadIdx.x;
    const int lane = t & 63;
    const int w = t >> 6;
    const int cl = w >> 1;                      // chunk-local 0,1
    const int kw = w & 1;                       // K-half 0,1
    const int chunk = blockIdx.x * 2 + cl;      // 0..1023
    const int plane = chunk >> 3;               // b*32+c
    const int i0 = (chunk & 7) << 4;            // 16 i-rows per chunk
    const int il = lane & 15;                   // i_local
    const int fg = lane >> 4;                   // k-subslice 0..3

    const float* xr0 = x + (long)plane * Hh * Ww + (long)(2 * (i0 + il)) * Ww;
    const float* xr1 = xr0 + Ww;
    const short* bp = Bg + (long)il * KTOT + fg * 8;

    f32x4 acc[4][8];
#pragma unroll
    for (int mi = 0; mi < 4; ++mi)
#pragma unroll
        for (int ni = 0; ni < 8; ++ni)
            acc[mi][ni] = (f32x4){0.f, 0.f, 0.f, 0.f};

#pragma unroll
    for (int jj = 0; jj < 2; ++jj) {
        const int jg = kw * 2 + jj;             // this wave's K-half
        const int cb = jg * 64 + fg * 16;       // x column base (16 floats)
        u32x4 afr[4][9];                        // A-fragments [mi][g]
#pragma unroll
        for (int p = 0; p < 4; ++p) {           // feature pairs
            f32x4 va = *(const f32x4*)(xr0 + cb + 4 * p);
            f32x4 vb = *(const f32x4*)(xr1 + cb + 4 * p);
            // Haar butterfly for both features of the pair
            float s01a = va[0] + va[1], d01a = va[0] - va[1];
            float s23a = vb[0] + vb[1], d23a = vb[0] - vb[1];
            float s01b = va[2] + va[3], d01b = va[2] - va[3];
            float s23b = vb[2] + vb[3], d23b = vb[2] - vb[3];
            float vkf[4][2];
            vkf[0][0] = 0.5f * (s01a + s23a); vkf[1][0] = 0.5f * (s01a - s23a);
            vkf[2][0] = 0.5f * (d01a + d23a); vkf[3][0] = 0.5f * (d01a - d23a);
            vkf[0][1] = 0.5f * (s01b + s23b); vkf[1][1] = 0.5f * (s01b - s23b);
            vkf[2][1] = 0.5f * (d01b + d23b); vkf[3][1] = 0.5f * (d01b - d23b);
#pragma unroll
            for (int mi = 0; mi < 4; ++mi) {
                float sl2[2]; unsigned Wf[2][4];
#pragma unroll
                for (int e = 0; e < 2; ++e) {
                    float v = vkf[mi][e];
                    float ex = __builtin_amdgcn_exp2f(-1.442695040888963f * v);
                    sl2[e] = v * __builtin_amdgcn_rcpf(1.0f + ex);      // silu
                    float xs = __builtin_fmaf(v, 2.5f, 5.5f);           // (v+2.2)*2.5
                    xs = fminf(fmaxf(xs, 0.0f), 10.999f);               // med3 clamp
                    float cf = floorf(xs);
                    float u = xs - cf;
                    int ci = (int)cf;                                   // 0..10
                    float u2 = u * u, u3 = u2 * u;
                    float wA = u3 * (1.f / 6.f);
                    float wB = (1.f + 3.f * u + 3.f * u2 - 3.f * u3) * (1.f / 6.f);
                    float wC = (4.f - 6.f * u2 + 3.f * u3) * (1.f / 6.f);
                    float um = 1.f - u;
                    float wD = um * um * um * (1.f / 6.f);
                    window128(wD, wC, wB, wA, ci, Wf[e]);
                }
                afr[mi][0][p] = pk_bf16(sl2[0], sl2[1]);
#pragma unroll
                for (int g = 1; g <= 8; ++g) {
                    int wq = (g - 1) >> 1;
                    unsigned sel = ((g - 1) & 1) ? 0x07060302u : 0x05040100u;
                    afr[mi][g][p] = __builtin_amdgcn_perm(Wf[1][wq], Wf[0][wq], sel);
                }
            }
        }
        // MFMA sweep: 9 k-steps x 4 row-tiles x 8 col-tiles
        const short* bk = bp + jg * KCH;
        __builtin_amdgcn_s_setprio(1);
#pragma unroll
        for (int ks = 0; ks < 9; ++ks) {
            s16x8 bfr[8];
#pragma unroll
            for (int ni = 0; ni < 8; ++ni)
                bfr[ni] = *(const s16x8*)&bk[(long)ni * 16 * KTOT + ks * 32];
#pragma unroll
            for (int mi = 0; mi < 4; ++mi) {
                s16x8 a = __builtin_bit_cast(s16x8, afr[mi][ks]);
#pragma unroll
                for (int ni = 0; ni < 8; ++ni)
                    acc[mi][ni] = __builtin_amdgcn_mfma_f32_16x16x32_bf16(
                        a, bfr[ni], acc[mi][ni], 0, 0, 0);
            }
        }
        __builtin_amdgcn_s_setprio(0);
    }

    // split-K reduce through LDS (conflict-free: lane stride = 4B)
    if (kw == 0) {
#pragma unroll
        for (int mi = 0; mi < 4; ++mi)
#pragma unroll
            for (int ni = 0; ni < 8; ++ni)
#pragma unroll
                for (int rr = 0; rr < 4; ++rr)
                    red[cl][mi * 32 + ni * 4 + rr][lane] = acc[mi][ni][rr];
    }
    __syncthreads();
    if (kw == 1) {
        // epilogue: local row = mi(kcomp)*16 + (fg*4+rr), col = ni*16 + il
#pragma unroll
        for (int mi = 0; mi < 4; ++mi) {
            long nb = ((long)(plane * 4 + mi) * H2 + i0) * NF;
#pragma unroll
            for (int rr = 0; rr < 4; ++rr) {
                long rowb = nb + (long)(fg * 4 + rr) * NF + il;
#pragma unroll
                for (int ni = 0; ni < 8; ++ni)
                    z[rowb + ni * 16] = acc[mi][ni][rr]
                                      + red[cl][mi * 32 + ni * 4 + rr][lane];
            }
        }
    }
}

// ---- K4: depthwise 5x5 conv + bias + inverse Haar -> out (final) ----
__global__ __launch_bounds__(256) void k_invconv(const float* __restrict__ x,
                                                 const float* __restrict__ cw,
                                                 const float* __restrict__ cb,
                                                 const float* __restrict__ z,
                                                 float* __restrict__ out) {
    __shared__ float sx[68][70];                // 19040 B, padded stride
    const int t = threadIdx.x;
    const int blk = blockIdx.x;
    const int tile = blk & 15;                  // 4x4 tiles of 64x64
    const int plane = blk >> 4;                 // b*32+c
    const int ty = tile >> 2, tx = tile & 3;
    const int c = plane & 31;
    const int Y0 = ty * 64, X0 = tx * 64;
    const float* xp = x + (long)plane * Hh * Ww;

    for (int idx = t; idx < 68 * 68; idx += 256) {
        int rr = idx / 68, cc2 = idx - rr * 68;
        int yy = Y0 - 2 + rr, xxp = X0 - 2 + cc2;
        float v = 0.f;
        if (yy >= 0 && yy < Hh && xxp >= 0 && xxp < Ww) v = xp[(long)yy * Ww + xxp];
        sx[rr][cc2] = v;
    }
    float w[25];
#pragma unroll
    for (int q = 0; q < 25; ++q) w[q] = cw[c * 25 + q];
    const float bias = cb[c];
    __syncthreads();

    const long zbase = (long)plane * 4 * H2 * W2;
    const long zplane = (long)H2 * W2;
#pragma unroll
    for (int p = 0; p < 4; ++p) {
        int q = t + p * 256;                    // quad id in 32x32
        int qy = q >> 5, qx = q & 31;
        int i = (Y0 >> 1) + qy, j = (X0 >> 1) + qx;
        long zi = zbase + (long)i * W2 + j;
        float z0 = z[zi];
        float z1 = z[zi + zplane];
        float z2 = z[zi + 2 * zplane];
        float z3 = z[zi + 3 * zplane];
        float y00 = 0.5f * (z0 + z1 + z2 + z3);
        float y01 = 0.5f * (z0 + z1 - z2 - z3);
        float y10 = 0.5f * (z0 - z1 + z2 - z3);
        float y11 = 0.5f * (z0 - z1 - z2 + z3);

        float vals[6][6];
#pragma unroll
        for (int rr = 0; rr < 6; ++rr)
#pragma unroll
            for (int c2 = 0; c2 < 3; ++c2) {
                float2 vv = *(const float2*)&sx[2 * qy + rr][2 * qx + 2 * c2];
                vals[rr][2 * c2] = vv.x; vals[rr][2 * c2 + 1] = vv.y;
            }
        float a00 = bias, a01 = bias, a10 = bias, a11 = bias;
#pragma unroll
        for (int ky = 0; ky < 5; ++ky)
#pragma unroll
            for (int kx = 0; kx < 5; ++kx) {
                float wvv = w[ky * 5 + kx];
                a00 += wvv * vals[ky][kx];
                a01 += wvv * vals[ky][kx + 1];
                a10 += wvv * vals[ky + 1][kx];
                a11 += wvv * vals[ky + 1][kx + 1];
            }
        float* op = out + (long)plane * Hh * Ww + (long)(Y0 + 2 * qy) * Ww + X0 + 2 * qx;
        *(float2*)op = make_float2(a00 + y00, a01 + y01);
        *(float2*)(op + Ww) = make_float2(a10 + y10, a11 + y11);
    }
}

extern "C" void kernel_launch(void* const* d_in, const int* in_sizes, int n_in,
                              void* d_out, int out_size, void* d_ws, size_t ws_size,
                              hipStream_t stream) {
    const float* x        = (const float*)d_in[0];
    const float* conv_w   = (const float*)d_in[1];
    const float* conv_b   = (const float*)d_in[2];
    const float* base_w   = (const float*)d_in[3];
    const float* spline_w = (const float*)d_in[4];
    const float* scaler   = (const float*)d_in[5];
    float* out = (float*)d_out;
    float* z   = (float*)d_ws;              // 65536 x 128 fp32 = 32 MiB
    short* Bg  = (short*)d_out;             // 288 KB staged in d_out (overwritten by k_invconv)

    // 1) fused bf16 weights into d_out scratch
    k_wbuild<<<(NF * KTOT) / 256, 256, 0, stream>>>(base_w, spline_w, scaler, Bg);
    // 2) split-K register-fragment KAN -> z (512 blocks = 2048 waves = 2/SIMD)
    k_fused<<<512, 256, 0, stream>>>(x, z, Bg);
    // 3) conv + inverse Haar -> out (fully overwrites d_out incl. Bg region)
    k_invconv<<<Bn * Cc * 16, 256, 0, stream>>>(x, conv_w, conv_b, z, out);
}

// Round 9
// 92.722 us; speedup vs baseline: 1.2029x; 1.2029x over previous
//
#include <hip/hip_runtime.h>
#include <hip/hip_bf16.h>

using f32x4 = __attribute__((ext_vector_type(4))) float;
using s16x8 = __attribute__((ext_vector_type(8))) short;
using u32x4 = __attribute__((ext_vector_type(4))) unsigned;

// Problem dims (fixed by reference setup_inputs)
constexpr int Bn = 4, Cc = 32, Hh = 256, Ww = 256;
constexpr int H2 = 128, W2 = 128;
constexpr int NF = 128;                 // KAN feature dim (= W2)
constexpr long NROWS = (long)Bn * Cc * 4 * H2;  // 65536 KAN rows
constexpr int KTOT = 1152;              // 128 features x 9 (silu + 8 bases)
constexpr int KCH = 288;                // K-chunk: 32 features x 9

// ---- bf16 round-to-nearest-even ----
__device__ __forceinline__ short f2bf(float f) {
    union { float f; unsigned u; } v; v.f = f;
    unsigned r = v.u + 0x7fffu + ((v.u >> 16) & 1u);
    return (short)(r >> 16);
}

// hardware bf16 pair pack (v_cvt_pk_bf16_f32)
__device__ __forceinline__ unsigned pk_bf16(float a, float b) {
    union { __hip_bfloat162 h; unsigned u; } c;
    c.h.x = __float2bfloat16(a);
    c.h.y = __float2bfloat16(b);
    return c.u;
}

// Place [wD,wC,wB,wA] (bf16-packed u64) at slot (ci-3) of an 8-slot 128-bit
// window; slots outside [0,7] dropped. ci guaranteed in [0,10] by caller.
__device__ __forceinline__ void window128(float wD, float wC, float wB, float wA,
                                          int ci, unsigned W[4]) {
    unsigned long long P = ((unsigned long long)pk_bf16(wB, wA) << 32)
                         | (unsigned long long)pk_bf16(wD, wC);
    int sh = ci * 16 - 48;
    unsigned long long sl = P << (sh & 63);
    unsigned long long sr = P >> ((-sh) & 63);
    unsigned long long lo = (sh < 0) ? sr : ((sh < 64) ? sl : 0ull);
    int shh = sh - 64;
    unsigned long long sl2 = P << (shh & 63);
    unsigned long long sr2 = P >> ((-shh) & 63);
    unsigned long long hi = (shh >= 0) ? sl2 : (((-shh) < 64) ? sr2 : 0ull);
    W[0] = (unsigned)lo; W[1] = (unsigned)(lo >> 32);
    W[2] = (unsigned)hi; W[3] = (unsigned)(hi >> 32);
}

// ---- KW: fused bf16 weight matrix Bg[o][k], k = jg*288 + g*32 + jl ----
__global__ __launch_bounds__(256) void k_wbuild(const float* __restrict__ base_w,
                                                const float* __restrict__ spline_w,
                                                const float* __restrict__ scaler,
                                                short* __restrict__ Bg) {
    int idx = blockIdx.x * 256 + threadIdx.x;
    int o = idx / KTOT;
    int k = idx - o * KTOT;
    int jg = k / KCH; int rem = k - jg * KCH;
    int g = rem >> 5; int jl = rem & 31;
    int j = jg * 32 + jl;
    float v = (g == 0) ? base_w[o * NF + j]
                       : spline_w[(long)(o * NF + j) * 8 + (g - 1)] * scaler[o * NF + j];
    Bg[idx] = f2bf(v);
}

// ---- K3: register-fragment KAN, split-K across wave pairs ----
// chunk = 16 i-rows x 4 kcomp x 128 cols; 2 waves/chunk (jg 0-1 / 2-3).
// 2048 waves; VGPR ~228 at (256,1) -> 2 waves/SIMD resident (no forced cap!).
__global__ __launch_bounds__(256, 1) void k_fused(const float* __restrict__ x,
                                                  float* __restrict__ z,
                                                  const short* __restrict__ Bg) {
    __shared__ float red[2][128][64];           // 64 KB: [chunk][mi*32+ni*4+rr][lane]
    const int t = threadIdx.x;
    const int lane = t & 63;
    const int w = t >> 6;
    const int cl = w >> 1;                      // chunk-local 0,1
    const int kw = w & 1;                       // K-half 0,1
    const int chunk = blockIdx.x * 2 + cl;      // 0..1023
    const int plane = chunk >> 3;               // b*32+c
    const int i0 = (chunk & 7) << 4;            // 16 i-rows per chunk
    const int il = lane & 15;                   // i_local
    const int fg = lane >> 4;                   // k-subslice 0..3

    const float* xr0 = x + (long)plane * Hh * Ww + (long)(2 * (i0 + il)) * Ww;
    const float* xr1 = xr0 + Ww;
    const short* bp = Bg + (long)il * KTOT + fg * 8;

    f32x4 acc[4][8];
#pragma unroll
    for (int mi = 0; mi < 4; ++mi)
#pragma unroll
        for (int ni = 0; ni < 8; ++ni)
            acc[mi][ni] = (f32x4){0.f, 0.f, 0.f, 0.f};

#pragma unroll
    for (int jj = 0; jj < 2; ++jj) {
        const int jg = kw * 2 + jj;             // this wave's K-half
        const int cb = jg * 64 + fg * 16;       // x column base (16 floats)
        u32x4 afr[4][9];                        // A-fragments [mi][g]
#pragma unroll
        for (int p = 0; p < 4; ++p) {           // feature pairs
            f32x4 va = *(const f32x4*)(xr0 + cb + 4 * p);
            f32x4 vb = *(const f32x4*)(xr1 + cb + 4 * p);
            // Haar butterfly for both features of the pair
            float s01a = va[0] + va[1], d01a = va[0] - va[1];
            float s23a = vb[0] + vb[1], d23a = vb[0] - vb[1];
            float s01b = va[2] + va[3], d01b = va[2] - va[3];
            float s23b = vb[2] + vb[3], d23b = vb[2] - vb[3];
            float vkf[4][2];
            vkf[0][0] = 0.5f * (s01a + s23a); vkf[1][0] = 0.5f * (s01a - s23a);
            vkf[2][0] = 0.5f * (d01a + d23a); vkf[3][0] = 0.5f * (d01a - d23a);
            vkf[0][1] = 0.5f * (s01b + s23b); vkf[1][1] = 0.5f * (s01b - s23b);
            vkf[2][1] = 0.5f * (d01b + d23b); vkf[3][1] = 0.5f * (d01b - d23b);
#pragma unroll
            for (int mi = 0; mi < 4; ++mi) {
                float sl2[2]; unsigned Wf[2][4];
#pragma unroll
                for (int e = 0; e < 2; ++e) {
                    float v = vkf[mi][e];
                    float ex = __builtin_amdgcn_exp2f(-1.442695040888963f * v);
                    sl2[e] = v * __builtin_amdgcn_rcpf(1.0f + ex);      // silu
                    float xs = __builtin_fmaf(v, 2.5f, 5.5f);           // (v+2.2)*2.5
                    xs = fminf(fmaxf(xs, 0.0f), 10.999f);               // med3 clamp
                    float cf = floorf(xs);
                    float u = xs - cf;
                    int ci = (int)cf;                                   // 0..10
                    float u2 = u * u, u3 = u2 * u;
                    float wA = u3 * (1.f / 6.f);
                    float wB = (1.f + 3.f * u + 3.f * u2 - 3.f * u3) * (1.f / 6.f);
                    float wC = (4.f - 6.f * u2 + 3.f * u3) * (1.f / 6.f);
                    float um = 1.f - u;
                    float wD = um * um * um * (1.f / 6.f);
                    window128(wD, wC, wB, wA, ci, Wf[e]);
                }
                afr[mi][0][p] = pk_bf16(sl2[0], sl2[1]);
#pragma unroll
                for (int g = 1; g <= 8; ++g) {
                    int wq = (g - 1) >> 1;
                    unsigned sel = ((g - 1) & 1) ? 0x07060302u : 0x05040100u;
                    afr[mi][g][p] = __builtin_amdgcn_perm(Wf[1][wq], Wf[0][wq], sel);
                }
            }
        }
        // MFMA sweep: 9 k-steps x 4 row-tiles x 8 col-tiles
        const short* bk = bp + jg * KCH;
        __builtin_amdgcn_s_setprio(1);
#pragma unroll
        for (int ks = 0; ks < 9; ++ks) {
            s16x8 bfr[8];
#pragma unroll
            for (int ni = 0; ni < 8; ++ni)
                bfr[ni] = *(const s16x8*)&bk[(long)ni * 16 * KTOT + ks * 32];
#pragma unroll
            for (int mi = 0; mi < 4; ++mi) {
                s16x8 a = __builtin_bit_cast(s16x8, afr[mi][ks]);
#pragma unroll
                for (int ni = 0; ni < 8; ++ni)
                    acc[mi][ni] = __builtin_amdgcn_mfma_f32_16x16x32_bf16(
                        a, bfr[ni], acc[mi][ni], 0, 0, 0);
            }
        }
        __builtin_amdgcn_s_setprio(0);
    }

    // split-K reduce through LDS (conflict-free: lane stride = 4B)
    if (kw == 0) {
#pragma unroll
        for (int mi = 0; mi < 4; ++mi)
#pragma unroll
            for (int ni = 0; ni < 8; ++ni)
#pragma unroll
                for (int rr = 0; rr < 4; ++rr)
                    red[cl][mi * 32 + ni * 4 + rr][lane] = acc[mi][ni][rr];
    }
    __syncthreads();
    if (kw == 1) {
        // epilogue: local row = mi(kcomp)*16 + (fg*4+rr), col = ni*16 + il
#pragma unroll
        for (int mi = 0; mi < 4; ++mi) {
            long nb = ((long)(plane * 4 + mi) * H2 + i0) * NF;
#pragma unroll
            for (int rr = 0; rr < 4; ++rr) {
                long rowb = nb + (long)(fg * 4 + rr) * NF + il;
#pragma unroll
                for (int ni = 0; ni < 8; ++ni)
                    z[rowb + ni * 16] = acc[mi][ni][rr]
                                      + red[cl][mi * 32 + ni * 4 + rr][lane];
            }
        }
    }
}

// ---- K4: depthwise 5x5 conv + bias + inverse Haar -> out (final) ----
__global__ __launch_bounds__(256) void k_invconv(const float* __restrict__ x,
                                                 const float* __restrict__ cw,
                                                 const float* __restrict__ cb,
                                                 const float* __restrict__ z,
                                                 float* __restrict__ out) {
    __shared__ float sx[68][70];                // 19040 B, padded stride
    const int t = threadIdx.x;
    const int blk = blockIdx.x;
    const int tile = blk & 15;                  // 4x4 tiles of 64x64
    const int plane = blk >> 4;                 // b*32+c
    const int ty = tile >> 2, tx = tile & 3;
    const int c = plane & 31;
    const int Y0 = ty * 64, X0 = tx * 64;
    const float* xp = x + (long)plane * Hh * Ww;

    for (int idx = t; idx < 68 * 68; idx += 256) {
        int rr = idx / 68, cc2 = idx - rr * 68;
        int yy = Y0 - 2 + rr, xxp = X0 - 2 + cc2;
        float v = 0.f;
        if (yy >= 0 && yy < Hh && xxp >= 0 && xxp < Ww) v = xp[(long)yy * Ww + xxp];
        sx[rr][cc2] = v;
    }
    float w[25];
#pragma unroll
    for (int q = 0; q < 25; ++q) w[q] = cw[c * 25 + q];
    const float bias = cb[c];
    __syncthreads();

    const long zbase = (long)plane * 4 * H2 * W2;
    const long zplane = (long)H2 * W2;
#pragma unroll
    for (int p = 0; p < 4; ++p) {
        int q = t + p * 256;                    // quad id in 32x32
        int qy = q >> 5, qx = q & 31;
        int i = (Y0 >> 1) + qy, j = (X0 >> 1) + qx;
        long zi = zbase + (long)i * W2 + j;
        float z0 = z[zi];
        float z1 = z[zi + zplane];
        float z2 = z[zi + 2 * zplane];
        float z3 = z[zi + 3 * zplane];
        float y00 = 0.5f * (z0 + z1 + z2 + z3);
        float y01 = 0.5f * (z0 + z1 - z2 - z3);
        float y10 = 0.5f * (z0 - z1 + z2 - z3);
        float y11 = 0.5f * (z0 - z1 - z2 + z3);

        float vals[6][6];
#pragma unroll
        for (int rr = 0; rr < 6; ++rr)
#pragma unroll
            for (int c2 = 0; c2 < 3; ++c2) {
                float2 vv = *(const float2*)&sx[2 * qy + rr][2 * qx + 2 * c2];
                vals[rr][2 * c2] = vv.x; vals[rr][2 * c2 + 1] = vv.y;
            }
        float a00 = bias, a01 = bias, a10 = bias, a11 = bias;
#pragma unroll
        for (int ky = 0; ky < 5; ++ky)
#pragma unroll
            for (int kx = 0; kx < 5; ++kx) {
                float wvv = w[ky * 5 + kx];
                a00 += wvv * vals[ky][kx];
                a01 += wvv * vals[ky][kx + 1];
                a10 += wvv * vals[ky + 1][kx];
                a11 += wvv * vals[ky + 1][kx + 1];
            }
        float* op = out + (long)plane * Hh * Ww + (long)(Y0 + 2 * qy) * Ww + X0 + 2 * qx;
        *(float2*)op = make_float2(a00 + y00, a01 + y01);
        *(float2*)(op + Ww) = make_float2(a10 + y10, a11 + y11);
    }
}

extern "C" void kernel_launch(void* const* d_in, const int* in_sizes, int n_in,
                              void* d_out, int out_size, void* d_ws, size_t ws_size,
                              hipStream_t stream) {
    const float* x        = (const float*)d_in[0];
    const float* conv_w   = (const float*)d_in[1];
    const float* conv_b   = (const float*)d_in[2];
    const float* base_w   = (const float*)d_in[3];
    const float* spline_w = (const float*)d_in[4];
    const float* scaler   = (const float*)d_in[5];
    float* out = (float*)d_out;
    float* z   = (float*)d_ws;              // 65536 x 128 fp32 = 32 MiB
    short* Bg  = (short*)d_out;             // 288 KB staged in d_out (overwritten by k_invconv)

    // 1) fused bf16 weights into d_out scratch
    k_wbuild<<<(NF * KTOT) / 256, 256, 0, stream>>>(base_w, spline_w, scaler, Bg);
    // 2) split-K register-fragment KAN -> z (512 blocks = 2048 waves = 2/SIMD)
    k_fused<<<512, 256, 0, stream>>>(x, z, Bg);
    // 3) conv + inverse Haar -> out (fully overwrites d_out incl. Bg region)
    k_invconv<<<Bn * Cc * 16, 256, 0, stream>>>(x, conv_w, conv_b, z, out);
}

// Round 10
// 77.760 us; speedup vs baseline: 1.4344x; 1.1924x over previous
//
#include <hip/hip_runtime.h>
#include <hip/hip_bf16.h>

using f32x4 = __attribute__((ext_vector_type(4))) float;
using s16x8 = __attribute__((ext_vector_type(8))) short;
using u32x4 = __attribute__((ext_vector_type(4))) unsigned;

// Problem dims (fixed by reference setup_inputs)
constexpr int Bn = 4, Cc = 32, Hh = 256, Ww = 256;
constexpr int H2 = 128, W2 = 128;
constexpr int NF = 128;                 // KAN feature dim (= W2)
constexpr long NROWS = (long)Bn * Cc * 4 * H2;  // 65536 KAN rows
constexpr int KTOT = 1152;              // 128 features x 9 (silu + 8 bases)
constexpr int KCH = 288;                // K-chunk: 32 features x 9

// ---- bf16 round-to-nearest-even ----
__device__ __forceinline__ short f2bf(float f) {
    union { float f; unsigned u; } v; v.f = f;
    unsigned r = v.u + 0x7fffu + ((v.u >> 16) & 1u);
    return (short)(r >> 16);
}

// hardware bf16 pair pack (v_cvt_pk_bf16_f32)
__device__ __forceinline__ unsigned pk_bf16(float a, float b) {
    union { __hip_bfloat162 h; unsigned u; } c;
    c.h.x = __float2bfloat16(a);
    c.h.y = __float2bfloat16(b);
    return c.u;
}

// Place [wD,wC,wB,wA] (bf16-packed u64) at slot (ci-3) of an 8-slot 128-bit
// window; slots outside [0,7] dropped. ci guaranteed in [0,10] by caller.
__device__ __forceinline__ void window128(float wD, float wC, float wB, float wA,
                                          int ci, unsigned W[4]) {
    unsigned long long P = ((unsigned long long)pk_bf16(wB, wA) << 32)
                         | (unsigned long long)pk_bf16(wD, wC);
    int sh = ci * 16 - 48;
    unsigned long long sl = P << (sh & 63);
    unsigned long long sr = P >> ((-sh) & 63);
    unsigned long long lo = (sh < 0) ? sr : ((sh < 64) ? sl : 0ull);
    int shh = sh - 64;
    unsigned long long sl2 = P << (shh & 63);
    unsigned long long sr2 = P >> ((-shh) & 63);
    unsigned long long hi = (shh >= 0) ? sl2 : (((-shh) < 64) ? sr2 : 0ull);
    W[0] = (unsigned)lo; W[1] = (unsigned)(lo >> 32);
    W[2] = (unsigned)hi; W[3] = (unsigned)(hi >> 32);
}

// ---- KW: bf16 weight matrix in MFMA-FRAGMENT order ----
// Bg[tile][lane][q], tile = (ni*4 + jg)*9 + ks  (ni:8, jg:4, ks:9 -> 288 tiles)
// lane holds col o = ni*16 + (lane&15), k = jg*288 + ks*32 + (lane>>4)*8 + q.
__global__ __launch_bounds__(256) void k_wbuild(const float* __restrict__ base_w,
                                                const float* __restrict__ spline_w,
                                                const float* __restrict__ scaler,
                                                short* __restrict__ Bg) {
    int idx = blockIdx.x * 256 + threadIdx.x;   // 147456 total
    int tile = idx >> 9;                        // /512 shorts per tile
    int r = idx & 511;
    int lane = r >> 3, q = r & 7;
    int ni = tile / 36; int rem = tile - ni * 36;
    int jg = rem / 9;   int ks = rem - jg * 9;
    int o = ni * 16 + (lane & 15);
    int kk = ks * 32 + (lane >> 4) * 8 + q;     // 0..287 within K-chunk
    int g = kk >> 5, jl = kk & 31;
    int j = jg * 32 + jl;
    float v = (g == 0) ? base_w[o * NF + j]
                       : spline_w[(long)(o * NF + j) * 8 + (g - 1)] * scaler[o * NF + j];
    Bg[idx] = f2bf(v);
}

// ---- K3: register-fragment KAN, split-K across wave pairs ----
// chunk = 16 i-rows x 4 kcomp x 128 cols; 2 waves/chunk (jg 0-1 / 2-3).
// 2048 waves; B-loads now perfectly coalesced (fragment-order Bg).
__global__ __launch_bounds__(256, 1) void k_fused(const float* __restrict__ x,
                                                  float* __restrict__ z,
                                                  const short* __restrict__ Bg) {
    __shared__ float red[2][128][64];           // 64 KB: [chunk][mi*32+ni*4+rr][lane]
    const int t = threadIdx.x;
    const int lane = t & 63;
    const int w = t >> 6;
    const int cl = w >> 1;                      // chunk-local 0,1
    const int kw = w & 1;                       // K-half 0,1
    const int chunk = blockIdx.x * 2 + cl;      // 0..1023
    const int plane = chunk >> 3;               // b*32+c
    const int i0 = (chunk & 7) << 4;            // 16 i-rows per chunk
    const int il = lane & 15;                   // i_local
    const int fg = lane >> 4;                   // k-subslice 0..3

    const float* xr0 = x + (long)plane * Hh * Ww + (long)(2 * (i0 + il)) * Ww;
    const float* xr1 = xr0 + Ww;
    const short* bl = Bg + lane * 8;            // per-lane fragment base

    f32x4 acc[4][8];
#pragma unroll
    for (int mi = 0; mi < 4; ++mi)
#pragma unroll
        for (int ni = 0; ni < 8; ++ni)
            acc[mi][ni] = (f32x4){0.f, 0.f, 0.f, 0.f};

#pragma unroll
    for (int jj = 0; jj < 2; ++jj) {
        const int jg = kw * 2 + jj;             // this wave's K-half
        const int cb = jg * 64 + fg * 16;       // x column base (16 floats)
        u32x4 afr[4][9];                        // A-fragments [mi][g]
#pragma unroll
        for (int p = 0; p < 4; ++p) {           // feature pairs
            f32x4 va = *(const f32x4*)(xr0 + cb + 4 * p);
            f32x4 vb = *(const f32x4*)(xr1 + cb + 4 * p);
            // Haar butterfly for both features of the pair
            float s01a = va[0] + va[1], d01a = va[0] - va[1];
            float s23a = vb[0] + vb[1], d23a = vb[0] - vb[1];
            float s01b = va[2] + va[3], d01b = va[2] - va[3];
            float s23b = vb[2] + vb[3], d23b = vb[2] - vb[3];
            float vkf[4][2];
            vkf[0][0] = 0.5f * (s01a + s23a); vkf[1][0] = 0.5f * (s01a - s23a);
            vkf[2][0] = 0.5f * (d01a + d23a); vkf[3][0] = 0.5f * (d01a - d23a);
            vkf[0][1] = 0.5f * (s01b + s23b); vkf[1][1] = 0.5f * (s01b - s23b);
            vkf[2][1] = 0.5f * (d01b + d23b); vkf[3][1] = 0.5f * (d01b - d23b);
#pragma unroll
            for (int mi = 0; mi < 4; ++mi) {
                float sl2[2]; unsigned Wf[2][4];
#pragma unroll
                for (int e = 0; e < 2; ++e) {
                    float v = vkf[mi][e];
                    float ex = __builtin_amdgcn_exp2f(-1.442695040888963f * v);
                    sl2[e] = v * __builtin_amdgcn_rcpf(1.0f + ex);      // silu
                    float xs = __builtin_fmaf(v, 2.5f, 5.5f);           // (v+2.2)*2.5
                    xs = fminf(fmaxf(xs, 0.0f), 10.999f);               // med3 clamp
                    float cf = floorf(xs);
                    float u = xs - cf;
                    int ci = (int)cf;                                   // 0..10
                    float u2 = u * u, u3 = u2 * u;
                    float wA = u3 * (1.f / 6.f);
                    float wB = (1.f + 3.f * u + 3.f * u2 - 3.f * u3) * (1.f / 6.f);
                    float wC = (4.f - 6.f * u2 + 3.f * u3) * (1.f / 6.f);
                    float um = 1.f - u;
                    float wD = um * um * um * (1.f / 6.f);
                    window128(wD, wC, wB, wA, ci, Wf[e]);
                }
                afr[mi][0][p] = pk_bf16(sl2[0], sl2[1]);
#pragma unroll
                for (int g = 1; g <= 8; ++g) {
                    int wq = (g - 1) >> 1;
                    unsigned sel = ((g - 1) & 1) ? 0x07060302u : 0x05040100u;
                    afr[mi][g][p] = __builtin_amdgcn_perm(Wf[1][wq], Wf[0][wq], sel);
                }
            }
        }
        // MFMA sweep: 9 k-steps x 4 row-tiles x 8 col-tiles.
        // B tile (ni,jg,ks) at Bg + ((ni*4+jg)*9 + ks)*512 shorts, coalesced.
        __builtin_amdgcn_s_setprio(1);
#pragma unroll
        for (int ks = 0; ks < 9; ++ks) {
            s16x8 bfr[8];
#pragma unroll
            for (int ni = 0; ni < 8; ++ni)
                bfr[ni] = *(const s16x8*)&bl[((ni * 4 + jg) * 9 + ks) * 512];
#pragma unroll
            for (int mi = 0; mi < 4; ++mi) {
                s16x8 a = __builtin_bit_cast(s16x8, afr[mi][ks]);
#pragma unroll
                for (int ni = 0; ni < 8; ++ni)
                    acc[mi][ni] = __builtin_amdgcn_mfma_f32_16x16x32_bf16(
                        a, bfr[ni], acc[mi][ni], 0, 0, 0);
            }
        }
        __builtin_amdgcn_s_setprio(0);
    }

    // split-K reduce through LDS (conflict-free: lane stride = 4B)
    if (kw == 0) {
#pragma unroll
        for (int mi = 0; mi < 4; ++mi)
#pragma unroll
            for (int ni = 0; ni < 8; ++ni)
#pragma unroll
                for (int rr = 0; rr < 4; ++rr)
                    red[cl][mi * 32 + ni * 4 + rr][lane] = acc[mi][ni][rr];
    }
    __syncthreads();
    if (kw == 1) {
        // epilogue: local row = mi(kcomp)*16 + (fg*4+rr), col = ni*16 + il
#pragma unroll
        for (int mi = 0; mi < 4; ++mi) {
            long nb = ((long)(plane * 4 + mi) * H2 + i0) * NF;
#pragma unroll
            for (int rr = 0; rr < 4; ++rr) {
                long rowb = nb + (long)(fg * 4 + rr) * NF + il;
#pragma unroll
                for (int ni = 0; ni < 8; ++ni)
                    z[rowb + ni * 16] = acc[mi][ni][rr]
                                      + red[cl][mi * 32 + ni * 4 + rr][lane];
            }
        }
    }
}

// ---- K4: depthwise 5x5 conv + bias + inverse Haar -> out (final) ----
__global__ __launch_bounds__(256) void k_invconv(const float* __restrict__ x,
                                                 const float* __restrict__ cw,
                                                 const float* __restrict__ cb,
                                                 const float* __restrict__ z,
                                                 float* __restrict__ out) {
    __shared__ float sx[68][70];                // 19040 B, padded stride
    const int t = threadIdx.x;
    const int blk = blockIdx.x;
    const int tile = blk & 15;                  // 4x4 tiles of 64x64
    const int plane = blk >> 4;                 // b*32+c
    const int ty = tile >> 2, tx = tile & 3;
    const int c = plane & 31;
    const int Y0 = ty * 64, X0 = tx * 64;
    const float* xp = x + (long)plane * Hh * Ww;

    for (int idx = t; idx < 68 * 68; idx += 256) {
        int rr = idx / 68, cc2 = idx - rr * 68;
        int yy = Y0 - 2 + rr, xxp = X0 - 2 + cc2;
        float v = 0.f;
        if (yy >= 0 && yy < Hh && xxp >= 0 && xxp < Ww) v = xp[(long)yy * Ww + xxp];
        sx[rr][cc2] = v;
    }
    float w[25];
#pragma unroll
    for (int q = 0; q < 25; ++q) w[q] = cw[c * 25 + q];
    const float bias = cb[c];
    __syncthreads();

    const long zbase = (long)plane * 4 * H2 * W2;
    const long zplane = (long)H2 * W2;
#pragma unroll
    for (int p = 0; p < 4; ++p) {
        int q = t + p * 256;                    // quad id in 32x32
        int qy = q >> 5, qx = q & 31;
        int i = (Y0 >> 1) + qy, j = (X0 >> 1) + qx;
        long zi = zbase + (long)i * W2 + j;
        float z0 = z[zi];
        float z1 = z[zi + zplane];
        float z2 = z[zi + 2 * zplane];
        float z3 = z[zi + 3 * zplane];
        float y00 = 0.5f * (z0 + z1 + z2 + z3);
        float y01 = 0.5f * (z0 + z1 - z2 - z3);
        float y10 = 0.5f * (z0 - z1 + z2 - z3);
        float y11 = 0.5f * (z0 - z1 - z2 + z3);

        float vals[6][6];
#pragma unroll
        for (int rr = 0; rr < 6; ++rr)
#pragma unroll
            for (int c2 = 0; c2 < 3; ++c2) {
                float2 vv = *(const float2*)&sx[2 * qy + rr][2 * qx + 2 * c2];
                vals[rr][2 * c2] = vv.x; vals[rr][2 * c2 + 1] = vv.y;
            }
        float a00 = bias, a01 = bias, a10 = bias, a11 = bias;
#pragma unroll
        for (int ky = 0; ky < 5; ++ky)
#pragma unroll
            for (int kx = 0; kx < 5; ++kx) {
                float wvv = w[ky * 5 + kx];
                a00 += wvv * vals[ky][kx];
                a01 += wvv * vals[ky][kx + 1];
                a10 += wvv * vals[ky + 1][kx];
                a11 += wvv * vals[ky + 1][kx + 1];
            }
        float* op = out + (long)plane * Hh * Ww + (long)(Y0 + 2 * qy) * Ww + X0 + 2 * qx;
        *(float2*)op = make_float2(a00 + y00, a01 + y01);
        *(float2*)(op + Ww) = make_float2(a10 + y10, a11 + y11);
    }
}

extern "C" void kernel_launch(void* const* d_in, const int* in_sizes, int n_in,
                              void* d_out, int out_size, void* d_ws, size_t ws_size,
                              hipStream_t stream) {
    const float* x        = (const float*)d_in[0];
    const float* conv_w   = (const float*)d_in[1];
    const float* conv_b   = (const float*)d_in[2];
    const float* base_w   = (const float*)d_in[3];
    const float* spline_w = (const float*)d_in[4];
    const float* scaler   = (const float*)d_in[5];
    float* out = (float*)d_out;
    float* z   = (float*)d_ws;              // 65536 x 128 fp32 = 32 MiB
    short* Bg  = (short*)d_out;             // 288 KB staged in d_out (overwritten by k_invconv)

    // 1) fragment-order bf16 weights into d_out scratch
    k_wbuild<<<(NF * KTOT) / 256, 256, 0, stream>>>(base_w, spline_w, scaler, Bg);
    // 2) split-K register-fragment KAN -> z (512 blocks = 2048 waves)
    k_fused<<<512, 256, 0, stream>>>(x, z, Bg);
    // 3) conv + inverse Haar -> out (fully overwrites d_out incl. Bg region)
    k_invconv<<<Bn * Cc * 16, 256, 0, stream>>>(x, conv_w, conv_b, z, out);
}

// Round 11
// 76.845 us; speedup vs baseline: 1.4515x; 1.0119x over previous
//
#include <hip/hip_runtime.h>
#include <hip/hip_bf16.h>

using f32x4 = __attribute__((ext_vector_type(4))) float;
using s16x8 = __attribute__((ext_vector_type(8))) short;
using u32x4 = __attribute__((ext_vector_type(4))) unsigned;

// Problem dims (fixed by reference setup_inputs)
constexpr int Bn = 4, Cc = 32, Hh = 256, Ww = 256;
constexpr int H2 = 128, W2 = 128;
constexpr int NF = 128;                 // KAN feature dim (= W2)
constexpr long NROWS = (long)Bn * Cc * 4 * H2;  // 65536 KAN rows
constexpr int KTOT = 1152;              // 128 features x 9 (silu + 8 bases)
constexpr int KCH = 288;                // K-chunk: 32 features x 9

// ---- bf16 round-to-nearest-even ----
__device__ __forceinline__ short f2bf(float f) {
    union { float f; unsigned u; } v; v.f = f;
    unsigned r = v.u + 0x7fffu + ((v.u >> 16) & 1u);
    return (short)(r >> 16);
}

// hardware bf16 pair pack (v_cvt_pk_bf16_f32)
__device__ __forceinline__ unsigned pk_bf16(float a, float b) {
    union { __hip_bfloat162 h; unsigned u; } c;
    c.h.x = __float2bfloat16(a);
    c.h.y = __float2bfloat16(b);
    return c.u;
}

// Place [wD,wC,wB,wA] (bf16-packed u64) at slot (ci-3) of an 8-slot 128-bit
// window; slots outside [0,7] dropped. ci guaranteed in [0,10] by caller.
__device__ __forceinline__ void window128(float wD, float wC, float wB, float wA,
                                          int ci, unsigned W[4]) {
    unsigned long long P = ((unsigned long long)pk_bf16(wB, wA) << 32)
                         | (unsigned long long)pk_bf16(wD, wC);
    int sh = ci * 16 - 48;
    unsigned long long sl = P << (sh & 63);
    unsigned long long sr = P >> ((-sh) & 63);
    unsigned long long lo = (sh < 0) ? sr : ((sh < 64) ? sl : 0ull);
    int shh = sh - 64;
    unsigned long long sl2 = P << (shh & 63);
    unsigned long long sr2 = P >> ((-shh) & 63);
    unsigned long long hi = (shh >= 0) ? sl2 : (((-shh) < 64) ? sr2 : 0ull);
    W[0] = (unsigned)lo; W[1] = (unsigned)(lo >> 32);
    W[2] = (unsigned)hi; W[3] = (unsigned)(hi >> 32);
}

// ---- KW: bf16 weight matrix in MFMA-FRAGMENT order ----
// Bg[tile][lane][q], tile = (ni*4 + jg)*9 + ks  (ni:8, jg:4, ks:9 -> 288 tiles)
// lane holds col o = ni*16 + (lane&15), k = jg*288 + ks*32 + (lane>>4)*8 + q.
__global__ __launch_bounds__(256) void k_wbuild(const float* __restrict__ base_w,
                                                const float* __restrict__ spline_w,
                                                const float* __restrict__ scaler,
                                                short* __restrict__ Bg) {
    int idx = blockIdx.x * 256 + threadIdx.x;   // 147456 total
    int tile = idx >> 9;                        // /512 shorts per tile
    int r = idx & 511;
    int lane = r >> 3, q = r & 7;
    int ni = tile / 36; int rem = tile - ni * 36;
    int jg = rem / 9;   int ks = rem - jg * 9;
    int o = ni * 16 + (lane & 15);
    int kk = ks * 32 + (lane >> 4) * 8 + q;     // 0..287 within K-chunk
    int g = kk >> 5, jl = kk & 31;
    int j = jg * 32 + jl;
    float v = (g == 0) ? base_w[o * NF + j]
                       : spline_w[(long)(o * NF + j) * 8 + (g - 1)] * scaler[o * NF + j];
    Bg[idx] = f2bf(v);
}

// ---- K3: register-fragment KAN, split-K pair per 128-thread block ----
// block = one chunk (16 i-rows x 4 kcomp x 128 cols), 2 waves: kw0 = jg{0,1},
// kw1 = jg{3,2} (reversed order -> phase/L2 stagger). 1024 blocks = 4/CU.
__global__ __launch_bounds__(128, 1) void k_fused(const float* __restrict__ x,
                                                  float* __restrict__ z,
                                                  const short* __restrict__ Bg) {
    __shared__ float red[128][64];              // 32 KB: [mi*32+ni*4+rr][lane]
    const int t = threadIdx.x;
    const int lane = t & 63;
    const int kw = t >> 6;                      // K-half 0,1
    const int chunk = blockIdx.x;               // 0..1023
    const int plane = chunk >> 3;               // b*32+c
    const int i0 = (chunk & 7) << 4;            // 16 i-rows per chunk
    const int il = lane & 15;                   // i_local
    const int fg = lane >> 4;                   // k-subslice 0..3

    const float* xr0 = x + (long)plane * Hh * Ww + (long)(2 * (i0 + il)) * Ww;
    const float* xr1 = xr0 + Ww;
    const short* bl = Bg + lane * 8;            // per-lane fragment base

    f32x4 acc[4][8];
#pragma unroll
    for (int mi = 0; mi < 4; ++mi)
#pragma unroll
        for (int ni = 0; ni < 8; ++ni)
            acc[mi][ni] = (f32x4){0.f, 0.f, 0.f, 0.f};

#pragma unroll
    for (int jj = 0; jj < 2; ++jj) {
        // kw0 walks jg = 0,1 ; kw1 walks jg = 3,2 (disjoint B tiles at any time)
        const int jg = kw ? (3 - jj) : jj;
        const int cb = jg * 64 + fg * 16;       // x column base (16 floats)
        u32x4 afr[4][9];                        // A-fragments [mi][g]
#pragma unroll
        for (int p = 0; p < 4; ++p) {           // feature pairs
            f32x4 va = *(const f32x4*)(xr0 + cb + 4 * p);
            f32x4 vb = *(const f32x4*)(xr1 + cb + 4 * p);
            // Haar butterfly for both features of the pair
            float s01a = va[0] + va[1], d01a = va[0] - va[1];
            float s23a = vb[0] + vb[1], d23a = vb[0] - vb[1];
            float s01b = va[2] + va[3], d01b = va[2] - va[3];
            float s23b = vb[2] + vb[3], d23b = vb[2] - vb[3];
            float vkf[4][2];
            vkf[0][0] = 0.5f * (s01a + s23a); vkf[1][0] = 0.5f * (s01a - s23a);
            vkf[2][0] = 0.5f * (d01a + d23a); vkf[3][0] = 0.5f * (d01a - d23a);
            vkf[0][1] = 0.5f * (s01b + s23b); vkf[1][1] = 0.5f * (s01b - s23b);
            vkf[2][1] = 0.5f * (d01b + d23b); vkf[3][1] = 0.5f * (d01b - d23b);
#pragma unroll
            for (int mi = 0; mi < 4; ++mi) {
                float sl2[2]; unsigned Wf[2][4];
#pragma unroll
                for (int e = 0; e < 2; ++e) {
                    float v = vkf[mi][e];
                    float ex = __builtin_amdgcn_exp2f(-1.442695040888963f * v);
                    sl2[e] = v * __builtin_amdgcn_rcpf(1.0f + ex);      // silu
                    float xs = __builtin_fmaf(v, 2.5f, 5.5f);           // (v+2.2)*2.5
                    xs = fminf(fmaxf(xs, 0.0f), 10.999f);               // med3 clamp
                    float cf = floorf(xs);
                    float u = xs - cf;
                    int ci = (int)cf;                                   // 0..10
                    float u2 = u * u, u3 = u2 * u;
                    float wA = u3 * (1.f / 6.f);
                    float wB = (1.f + 3.f * u + 3.f * u2 - 3.f * u3) * (1.f / 6.f);
                    float wC = (4.f - 6.f * u2 + 3.f * u3) * (1.f / 6.f);
                    float um = 1.f - u;
                    float wD = um * um * um * (1.f / 6.f);
                    window128(wD, wC, wB, wA, ci, Wf[e]);
                }
                afr[mi][0][p] = pk_bf16(sl2[0], sl2[1]);
#pragma unroll
                for (int g = 1; g <= 8; ++g) {
                    int wq = (g - 1) >> 1;
                    unsigned sel = ((g - 1) & 1) ? 0x07060302u : 0x05040100u;
                    afr[mi][g][p] = __builtin_amdgcn_perm(Wf[1][wq], Wf[0][wq], sel);
                }
            }
        }
        // MFMA sweep: 9 k-steps x 4 row-tiles x 8 col-tiles.
        // B tile (ni,jg,ks) at Bg + ((ni*4+jg)*9 + ks)*512 shorts, coalesced.
#pragma unroll
        for (int ks = 0; ks < 9; ++ks) {
            s16x8 bfr[8];
#pragma unroll
            for (int ni = 0; ni < 8; ++ni)
                bfr[ni] = *(const s16x8*)&bl[((ni * 4 + jg) * 9 + ks) * 512];
#pragma unroll
            for (int mi = 0; mi < 4; ++mi) {
                s16x8 a = __builtin_bit_cast(s16x8, afr[mi][ks]);
#pragma unroll
                for (int ni = 0; ni < 8; ++ni)
                    acc[mi][ni] = __builtin_amdgcn_mfma_f32_16x16x32_bf16(
                        a, bfr[ni], acc[mi][ni], 0, 0, 0);
            }
        }
    }

    // split-K reduce through LDS (conflict-free: lane stride = 4B)
    if (kw == 0) {
#pragma unroll
        for (int mi = 0; mi < 4; ++mi)
#pragma unroll
            for (int ni = 0; ni < 8; ++ni)
#pragma unroll
                for (int rr = 0; rr < 4; ++rr)
                    red[mi * 32 + ni * 4 + rr][lane] = acc[mi][ni][rr];
    }
    __syncthreads();
    if (kw == 1) {
        // epilogue: local row = mi(kcomp)*16 + (fg*4+rr), col = ni*16 + il
#pragma unroll
        for (int mi = 0; mi < 4; ++mi) {
            long nb = ((long)(plane * 4 + mi) * H2 + i0) * NF;
#pragma unroll
            for (int rr = 0; rr < 4; ++rr) {
                long rowb = nb + (long)(fg * 4 + rr) * NF + il;
#pragma unroll
                for (int ni = 0; ni < 8; ++ni)
                    z[rowb + ni * 16] = acc[mi][ni][rr]
                                      + red[mi * 32 + ni * 4 + rr][lane];
            }
        }
    }
}

// ---- K4: depthwise 5x5 conv + bias + inverse Haar -> out (final) ----
__global__ __launch_bounds__(256) void k_invconv(const float* __restrict__ x,
                                                 const float* __restrict__ cw,
                                                 const float* __restrict__ cb,
                                                 const float* __restrict__ z,
                                                 float* __restrict__ out) {
    __shared__ float sx[68][70];                // 19040 B, padded stride
    const int t = threadIdx.x;
    const int blk = blockIdx.x;
    const int tile = blk & 15;                  // 4x4 tiles of 64x64
    const int plane = blk >> 4;                 // b*32+c
    const int ty = tile >> 2, tx = tile & 3;
    const int c = plane & 31;
    const int Y0 = ty * 64, X0 = tx * 64;
    const float* xp = x + (long)plane * Hh * Ww;

    for (int idx = t; idx < 68 * 68; idx += 256) {
        int rr = idx / 68, cc2 = idx - rr * 68;
        int yy = Y0 - 2 + rr, xxp = X0 - 2 + cc2;
        float v = 0.f;
        if (yy >= 0 && yy < Hh && xxp >= 0 && xxp < Ww) v = xp[(long)yy * Ww + xxp];
        sx[rr][cc2] = v;
    }
    float w[25];
#pragma unroll
    for (int q = 0; q < 25; ++q) w[q] = cw[c * 25 + q];
    const float bias = cb[c];
    __syncthreads();

    const long zbase = (long)plane * 4 * H2 * W2;
    const long zplane = (long)H2 * W2;
#pragma unroll
    for (int p = 0; p < 4; ++p) {
        int q = t + p * 256;                    // quad id in 32x32
        int qy = q >> 5, qx = q & 31;
        int i = (Y0 >> 1) + qy, j = (X0 >> 1) + qx;
        long zi = zbase + (long)i * W2 + j;
        float z0 = z[zi];
        float z1 = z[zi + zplane];
        float z2 = z[zi + 2 * zplane];
        float z3 = z[zi + 3 * zplane];
        float y00 = 0.5f * (z0 + z1 + z2 + z3);
        float y01 = 0.5f * (z0 + z1 - z2 - z3);
        float y10 = 0.5f * (z0 - z1 + z2 - z3);
        float y11 = 0.5f * (z0 - z1 - z2 + z3);

        float vals[6][6];
#pragma unroll
        for (int rr = 0; rr < 6; ++rr)
#pragma unroll
            for (int c2 = 0; c2 < 3; ++c2) {
                float2 vv = *(const float2*)&sx[2 * qy + rr][2 * qx + 2 * c2];
                vals[rr][2 * c2] = vv.x; vals[rr][2 * c2 + 1] = vv.y;
            }
        float a00 = bias, a01 = bias, a10 = bias, a11 = bias;
#pragma unroll
        for (int ky = 0; ky < 5; ++ky)
#pragma unroll
            for (int kx = 0; kx < 5; ++kx) {
                float wvv = w[ky * 5 + kx];
                a00 += wvv * vals[ky][kx];
                a01 += wvv * vals[ky][kx + 1];
                a10 += wvv * vals[ky + 1][kx];
                a11 += wvv * vals[ky + 1][kx + 1];
            }
        float* op = out + (long)plane * Hh * Ww + (long)(Y0 + 2 * qy) * Ww + X0 + 2 * qx;
        *(float2*)op = make_float2(a00 + y00, a01 + y01);
        *(float2*)(op + Ww) = make_float2(a10 + y10, a11 + y11);
    }
}

extern "C" void kernel_launch(void* const* d_in, const int* in_sizes, int n_in,
                              void* d_out, int out_size, void* d_ws, size_t ws_size,
                              hipStream_t stream) {
    const float* x        = (const float*)d_in[0];
    const float* conv_w   = (const float*)d_in[1];
    const float* conv_b   = (const float*)d_in[2];
    const float* base_w   = (const float*)d_in[3];
    const float* spline_w = (const float*)d_in[4];
    const float* scaler   = (const float*)d_in[5];
    float* out = (float*)d_out;
    float* z   = (float*)d_ws;              // 65536 x 128 fp32 = 32 MiB
    short* Bg  = (short*)d_out;             // 288 KB staged in d_out (overwritten by k_invconv)

    // 1) fragment-order bf16 weights into d_out scratch
    k_wbuild<<<(NF * KTOT) / 256, 256, 0, stream>>>(base_w, spline_w, scaler, Bg);
    // 2) split-K register-fragment KAN -> z (1024 blocks x 128 thr = 2048 waves)
    k_fused<<<1024, 128, 0, stream>>>(x, z, Bg);
    // 3) conv + inverse Haar -> out (fully overwrites d_out incl. Bg region)
    k_invconv<<<Bn * Cc * 16, 256, 0, stream>>>(x, conv_w, conv_b, z, out);
}

// Round 12
// 68.965 us; speedup vs baseline: 1.6173x; 1.1143x over previous
//
#include <hip/hip_runtime.h>
#include <hip/hip_bf16.h>

using f32x4 = __attribute__((ext_vector_type(4))) float;
using s16x8 = __attribute__((ext_vector_type(8))) short;
using u32x4 = __attribute__((ext_vector_type(4))) unsigned;

// Problem dims (fixed by reference setup_inputs)
constexpr int Bn = 4, Cc = 32, Hh = 256, Ww = 256;
constexpr int H2 = 128, W2 = 128;
constexpr int NF = 128;                 // KAN feature dim (= W2)
constexpr long NROWS = (long)Bn * Cc * 4 * H2;  // 65536 KAN rows
constexpr int KTOT = 1152;              // 128 features x 9 (silu + 8 bases)
constexpr int KCH = 288;                // K-chunk: 32 features x 9

// ---- bf16 round-to-nearest-even ----
__device__ __forceinline__ short f2bf(float f) {
    union { float f; unsigned u; } v; v.f = f;
    unsigned r = v.u + 0x7fffu + ((v.u >> 16) & 1u);
    return (short)(r >> 16);
}

// hardware bf16 pair pack (v_cvt_pk_bf16_f32)
__device__ __forceinline__ unsigned pk_bf16(float a, float b) {
    union { __hip_bfloat162 h; unsigned u; } c;
    c.h.x = __float2bfloat16(a);
    c.h.y = __float2bfloat16(b);
    return c.u;
}

// Place [wD,wC,wB,wA] (bf16-packed u64) at slot (ci-3) of an 8-slot 128-bit
// window; slots outside [0,7] dropped. ci guaranteed in [0,10] by caller.
__device__ __forceinline__ void window128(float wD, float wC, float wB, float wA,
                                          int ci, unsigned W[4]) {
    unsigned long long P = ((unsigned long long)pk_bf16(wB, wA) << 32)
                         | (unsigned long long)pk_bf16(wD, wC);
    int sh = ci * 16 - 48;
    unsigned long long sl = P << (sh & 63);
    unsigned long long sr = P >> ((-sh) & 63);
    unsigned long long lo = (sh < 0) ? sr : ((sh < 64) ? sl : 0ull);
    int shh = sh - 64;
    unsigned long long sl2 = P << (shh & 63);
    unsigned long long sr2 = P >> ((-shh) & 63);
    unsigned long long hi = (shh >= 0) ? sl2 : (((-shh) < 64) ? sr2 : 0ull);
    W[0] = (unsigned)lo; W[1] = (unsigned)(lo >> 32);
    W[2] = (unsigned)hi; W[3] = (unsigned)(hi >> 32);
}

// ---- KW: bf16 weight matrix in MFMA-FRAGMENT order ----
// Bg[tile][lane][q], tile = (ni*4 + jg)*9 + ks  (ni:8, jg:4, ks:9 -> 288 tiles)
// lane holds col o = ni*16 + (lane&15), k = jg*288 + ks*32 + (lane>>4)*8 + q.
__global__ __launch_bounds__(256) void k_wbuild(const float* __restrict__ base_w,
                                                const float* __restrict__ spline_w,
                                                const float* __restrict__ scaler,
                                                short* __restrict__ Bg) {
    int idx = blockIdx.x * 256 + threadIdx.x;   // 147456 total
    int tile = idx >> 9;                        // /512 shorts per tile
    int r = idx & 511;
    int lane = r >> 3, q = r & 7;
    int ni = tile / 36; int rem = tile - ni * 36;
    int jg = rem / 9;   int ks = rem - jg * 9;
    int o = ni * 16 + (lane & 15);
    int kk = ks * 32 + (lane >> 4) * 8 + q;     // 0..287 within K-chunk
    int g = kk >> 5, jl = kk & 31;
    int j = jg * 32 + jl;
    float v = (g == 0) ? base_w[o * NF + j]
                       : spline_w[(long)(o * NF + j) * 8 + (g - 1)] * scaler[o * NF + j];
    Bg[idx] = f2bf(v);
}

// ---- K3: register-fragment KAN, kcomp-split (2 Haar comps per wave) ----
// wave = 16 i-rows x 2 kcomp x 128 cols x full K. acc[2][8]=64 AGPR,
// afr[2][9]=72 VGPR -> ~210 total unified regs -> 2 waves/SIMD resident.
// No LDS, no barriers, no split-K reduce. 1024 blocks x 128 thr = 2048 waves.
__global__ __launch_bounds__(128, 2) void k_fused(const float* __restrict__ x,
                                                  float* __restrict__ z,
                                                  const short* __restrict__ Bg) {
    const int t = threadIdx.x;
    const int lane = t & 63;
    const int kp = t >> 6;                      // kcomp pair: 0 -> {0,1}, 1 -> {2,3}
    const int chunk = blockIdx.x;               // 0..1023
    const int plane = chunk >> 3;               // b*32+c
    const int i0 = (chunk & 7) << 4;            // 16 i-rows per chunk
    const int il = lane & 15;                   // i_local (MFMA A-row / C-col)
    const int fg = lane >> 4;                   // k-subslice 0..3

    const float* xr0 = x + (long)plane * Hh * Ww + (long)(2 * (i0 + il)) * Ww;
    const float* xr1 = xr0 + Ww;
    const short* bl = Bg + lane * 8;            // per-lane fragment base

    f32x4 acc[2][8];
#pragma unroll
    for (int mi = 0; mi < 2; ++mi)
#pragma unroll
        for (int ni = 0; ni < 8; ++ni)
            acc[mi][ni] = (f32x4){0.f, 0.f, 0.f, 0.f};

    for (int jg = 0; jg < 4; ++jg) {
        const int cb = jg * 64 + fg * 16;       // x column base (16 floats)
        u32x4 afr[2][9];                        // A-fragments [mi2][g]
#pragma unroll
        for (int p = 0; p < 4; ++p) {           // feature pairs
            f32x4 va = *(const f32x4*)(xr0 + cb + 4 * p);
            f32x4 vb = *(const f32x4*)(xr1 + cb + 4 * p);
            // Haar butterfly halves: kp=0 needs sums, kp=1 needs diffs
            float s01a = va[0] + va[1], d01a = va[0] - va[1];
            float s23a = vb[0] + vb[1], d23a = vb[0] - vb[1];
            float s01b = va[2] + va[3], d01b = va[2] - va[3];
            float s23b = vb[2] + vb[3], d23b = vb[2] - vb[3];
            float ua = kp ? d01a : s01a, wa = kp ? d23a : s23a;
            float ub = kp ? d01b : s01b, wb2 = kp ? d23b : s23b;
            float vkf[2][2];
            vkf[0][0] = 0.5f * (ua + wa); vkf[1][0] = 0.5f * (ua - wa);
            vkf[0][1] = 0.5f * (ub + wb2); vkf[1][1] = 0.5f * (ub - wb2);
#pragma unroll
            for (int mi = 0; mi < 2; ++mi) {
                float sl2[2]; unsigned Wf[2][4];
#pragma unroll
                for (int e = 0; e < 2; ++e) {
                    float v = vkf[mi][e];
                    float ex = __builtin_amdgcn_exp2f(-1.442695040888963f * v);
                    sl2[e] = v * __builtin_amdgcn_rcpf(1.0f + ex);      // silu
                    float xs = __builtin_fmaf(v, 2.5f, 5.5f);           // (v+2.2)*2.5
                    xs = fminf(fmaxf(xs, 0.0f), 10.999f);               // med3 clamp
                    float cf = floorf(xs);
                    float u = xs - cf;
                    int ci = (int)cf;                                   // 0..10
                    float u2 = u * u, u3 = u2 * u;
                    float wA = u3 * (1.f / 6.f);
                    float wB = (1.f + 3.f * u + 3.f * u2 - 3.f * u3) * (1.f / 6.f);
                    float wC = (4.f - 6.f * u2 + 3.f * u3) * (1.f / 6.f);
                    float um = 1.f - u;
                    float wD = um * um * um * (1.f / 6.f);
                    window128(wD, wC, wB, wA, ci, Wf[e]);
                }
                afr[mi][0][p] = pk_bf16(sl2[0], sl2[1]);
#pragma unroll
                for (int g = 1; g <= 8; ++g) {
                    int wq = (g - 1) >> 1;
                    unsigned sel = ((g - 1) & 1) ? 0x07060302u : 0x05040100u;
                    afr[mi][g][p] = __builtin_amdgcn_perm(Wf[1][wq], Wf[0][wq], sel);
                }
            }
        }
        // MFMA sweep: 9 k-steps x 2 row-tiles x 8 col-tiles.
        // B tile (ni,jg,ks) at Bg + ((ni*4+jg)*9 + ks)*512 shorts, coalesced.
#pragma unroll
        for (int ks = 0; ks < 9; ++ks) {
            s16x8 bfr[8];
#pragma unroll
            for (int ni = 0; ni < 8; ++ni)
                bfr[ni] = *(const s16x8*)&bl[((ni * 4 + jg) * 9 + ks) * 512];
#pragma unroll
            for (int mi = 0; mi < 2; ++mi) {
                s16x8 a = __builtin_bit_cast(s16x8, afr[mi][ks]);
#pragma unroll
                for (int ni = 0; ni < 8; ++ni)
                    acc[mi][ni] = __builtin_amdgcn_mfma_f32_16x16x32_bf16(
                        a, bfr[ni], acc[mi][ni], 0, 0, 0);
            }
        }
    }

    // epilogue: kcomp = kp*2+mi; z row = i0 + fg*4+rr, col = ni*16 + il
#pragma unroll
    for (int mi = 0; mi < 2; ++mi) {
        const int kcomp = kp * 2 + mi;
        long nb = ((long)(plane * 4 + kcomp) * H2 + i0) * NF;
#pragma unroll
        for (int rr = 0; rr < 4; ++rr) {
            long rowb = nb + (long)(fg * 4 + rr) * NF + il;
#pragma unroll
            for (int ni = 0; ni < 8; ++ni)
                z[rowb + ni * 16] = acc[mi][ni][rr];
        }
    }
}

// ---- K4: depthwise 5x5 conv + bias + inverse Haar -> out (final) ----
__global__ __launch_bounds__(256) void k_invconv(const float* __restrict__ x,
                                                 const float* __restrict__ cw,
                                                 const float* __restrict__ cb,
                                                 const float* __restrict__ z,
                                                 float* __restrict__ out) {
    __shared__ float sx[68][70];                // 19040 B, padded stride
    const int t = threadIdx.x;
    const int blk = blockIdx.x;
    const int tile = blk & 15;                  // 4x4 tiles of 64x64
    const int plane = blk >> 4;                 // b*32+c
    const int ty = tile >> 2, tx = tile & 3;
    const int c = plane & 31;
    const int Y0 = ty * 64, X0 = tx * 64;
    const float* xp = x + (long)plane * Hh * Ww;

    for (int idx = t; idx < 68 * 68; idx += 256) {
        int rr = idx / 68, cc2 = idx - rr * 68;
        int yy = Y0 - 2 + rr, xxp = X0 - 2 + cc2;
        float v = 0.f;
        if (yy >= 0 && yy < Hh && xxp >= 0 && xxp < Ww) v = xp[(long)yy * Ww + xxp];
        sx[rr][cc2] = v;
    }
    float w[25];
#pragma unroll
    for (int q = 0; q < 25; ++q) w[q] = cw[c * 25 + q];
    const float bias = cb[c];
    __syncthreads();

    const long zbase = (long)plane * 4 * H2 * W2;
    const long zplane = (long)H2 * W2;
#pragma unroll
    for (int p = 0; p < 4; ++p) {
        int q = t + p * 256;                    // quad id in 32x32
        int qy = q >> 5, qx = q & 31;
        int i = (Y0 >> 1) + qy, j = (X0 >> 1) + qx;
        long zi = zbase + (long)i * W2 + j;
        float z0 = z[zi];
        float z1 = z[zi + zplane];
        float z2 = z[zi + 2 * zplane];
        float z3 = z[zi + 3 * zplane];
        float y00 = 0.5f * (z0 + z1 + z2 + z3);
        float y01 = 0.5f * (z0 + z1 - z2 - z3);
        float y10 = 0.5f * (z0 - z1 + z2 - z3);
        float y11 = 0.5f * (z0 - z1 - z2 + z3);

        float vals[6][6];
#pragma unroll
        for (int rr = 0; rr < 6; ++rr)
#pragma unroll
            for (int c2 = 0; c2 < 3; ++c2) {
                float2 vv = *(const float2*)&sx[2 * qy + rr][2 * qx + 2 * c2];
                vals[rr][2 * c2] = vv.x; vals[rr][2 * c2 + 1] = vv.y;
            }
        float a00 = bias, a01 = bias, a10 = bias, a11 = bias;
#pragma unroll
        for (int ky = 0; ky < 5; ++ky)
#pragma unroll
            for (int kx = 0; kx < 5; ++kx) {
                float wvv = w[ky * 5 + kx];
                a00 += wvv * vals[ky][kx];
                a01 += wvv * vals[ky][kx + 1];
                a10 += wvv * vals[ky + 1][kx];
                a11 += wvv * vals[ky + 1][kx + 1];
            }
        float* op = out + (long)plane * Hh * Ww + (long)(Y0 + 2 * qy) * Ww + X0 + 2 * qx;
        *(float2*)op = make_float2(a00 + y00, a01 + y01);
        *(float2*)(op + Ww) = make_float2(a10 + y10, a11 + y11);
    }
}

extern "C" void kernel_launch(void* const* d_in, const int* in_sizes, int n_in,
                              void* d_out, int out_size, void* d_ws, size_t ws_size,
                              hipStream_t stream) {
    const float* x        = (const float*)d_in[0];
    const float* conv_w   = (const float*)d_in[1];
    const float* conv_b   = (const float*)d_in[2];
    const float* base_w   = (const float*)d_in[3];
    const float* spline_w = (const float*)d_in[4];
    const float* scaler   = (const float*)d_in[5];
    float* out = (float*)d_out;
    float* z   = (float*)d_ws;              // 65536 x 128 fp32 = 32 MiB
    short* Bg  = (short*)d_out;             // 288 KB staged in d_out (overwritten by k_invconv)

    // 1) fragment-order bf16 weights into d_out scratch
    k_wbuild<<<(NF * KTOT) / 256, 256, 0, stream>>>(base_w, spline_w, scaler, Bg);
    // 2) kcomp-split register-fragment KAN -> z (1024 blocks x 128 thr)
    k_fused<<<1024, 128, 0, stream>>>(x, z, Bg);
    // 3) conv + inverse Haar -> out (fully overwrites d_out incl. Bg region)
    k_invconv<<<Bn * Cc * 16, 256, 0, stream>>>(x, conv_w, conv_b, z, out);
}

// Round 13
// 65.713 us; speedup vs baseline: 1.6974x; 1.0495x over previous
//
#include <hip/hip_runtime.h>
#include <hip/hip_bf16.h>

using f32x4 = __attribute__((ext_vector_type(4))) float;
using s16x8 = __attribute__((ext_vector_type(8))) short;
using u32x4 = __attribute__((ext_vector_type(4))) unsigned;

// Problem dims (fixed by reference setup_inputs)
constexpr int Bn = 4, Cc = 32, Hh = 256, Ww = 256;
constexpr int H2 = 128, W2 = 128;
constexpr int NF = 128;                 // KAN feature dim (= W2)
constexpr long NROWS = (long)Bn * Cc * 4 * H2;  // 65536 KAN rows
constexpr int KTOT = 1152;              // 128 features x 9 (silu + 8 bases)
constexpr int KCH = 288;                // K-chunk: 32 features x 9

// ---- bf16 round-to-nearest-even ----
__device__ __forceinline__ short f2bf(float f) {
    union { float f; unsigned u; } v; v.f = f;
    unsigned r = v.u + 0x7fffu + ((v.u >> 16) & 1u);
    return (short)(r >> 16);
}

// hardware bf16 pair pack (v_cvt_pk_bf16_f32)
__device__ __forceinline__ unsigned pk_bf16(float a, float b) {
    union { __hip_bfloat162 h; unsigned u; } c;
    c.h.x = __float2bfloat16(a);
    c.h.y = __float2bfloat16(b);
    return c.u;
}

// Place [wD,wC,wB,wA] (bf16-packed u64) at slot (ci-3) of an 8-slot 128-bit
// window; slots outside [0,7] dropped. ci guaranteed in [0,10] by caller.
__device__ __forceinline__ void window128(float wD, float wC, float wB, float wA,
                                          int ci, unsigned W[4]) {
    unsigned long long P = ((unsigned long long)pk_bf16(wB, wA) << 32)
                         | (unsigned long long)pk_bf16(wD, wC);
    int sh = ci * 16 - 48;
    unsigned long long sl = P << (sh & 63);
    unsigned long long sr = P >> ((-sh) & 63);
    unsigned long long lo = (sh < 0) ? sr : ((sh < 64) ? sl : 0ull);
    int shh = sh - 64;
    unsigned long long sl2 = P << (shh & 63);
    unsigned long long sr2 = P >> ((-shh) & 63);
    unsigned long long hi = (shh >= 0) ? sl2 : (((-shh) < 64) ? sr2 : 0ull);
    W[0] = (unsigned)lo; W[1] = (unsigned)(lo >> 32);
    W[2] = (unsigned)hi; W[3] = (unsigned)(hi >> 32);
}

// ---- KW: bf16 weight matrix in MFMA-FRAGMENT order ----
// Bg[tile][lane][q], tile = (ni*4 + jg)*9 + ks  (ni:8, jg:4, ks:9 -> 288 tiles)
// lane holds col o = ni*16 + (lane&15), k = jg*288 + ks*32 + (lane>>4)*8 + q.
__global__ __launch_bounds__(256) void k_wbuild(const float* __restrict__ base_w,
                                                const float* __restrict__ spline_w,
                                                const float* __restrict__ scaler,
                                                short* __restrict__ Bg) {
    int idx = blockIdx.x * 256 + threadIdx.x;   // 147456 total
    int tile = idx >> 9;                        // /512 shorts per tile
    int r = idx & 511;
    int lane = r >> 3, q = r & 7;
    int ni = tile / 36; int rem = tile - ni * 36;
    int jg = rem / 9;   int ks = rem - jg * 9;
    int o = ni * 16 + (lane & 15);
    int kk = ks * 32 + (lane >> 4) * 8 + q;     // 0..287 within K-chunk
    int g = kk >> 5, jl = kk & 31;
    int j = jg * 32 + jl;
    float v = (g == 0) ? base_w[o * NF + j]
                       : spline_w[(long)(o * NF + j) * 8 + (g - 1)] * scaler[o * NF + j];
    Bg[idx] = f2bf(v);
}

#define LOADB(dst, ksv)                                                        \
    _Pragma("unroll")                                                          \
    for (int ni = 0; ni < 8; ++ni)                                             \
        dst[ni] = *(const s16x8*)&bl[((ni * 4 + jg) * 9 + (ksv)) * 512];

#define MFMA_STEP(buf, ksv)                                                    \
    _Pragma("unroll")                                                          \
    for (int mi = 0; mi < 2; ++mi) {                                           \
        s16x8 a = __builtin_bit_cast(s16x8, afr[mi][ksv]);                     \
        _Pragma("unroll")                                                      \
        for (int ni = 0; ni < 8; ++ni)                                         \
            acc[mi][ni] = __builtin_amdgcn_mfma_f32_16x16x32_bf16(             \
                a, buf[ni], acc[mi][ni], 0, 0, 0);                             \
    }

// ---- K3: register-fragment KAN, kcomp-split, B double-buffer pipelined ----
// wave = 16 i-rows x 2 kcomp x 128 cols x full K. 1024 blocks x 128 thr.
__global__ __launch_bounds__(128, 2) void k_fused(const float* __restrict__ x,
                                                  float* __restrict__ z,
                                                  const short* __restrict__ Bg) {
    const int t = threadIdx.x;
    const int lane = t & 63;
    const int kp = t >> 6;                      // kcomp pair: 0 -> {0,1}, 1 -> {2,3}
    const int chunk = blockIdx.x;               // 0..1023
    const int plane = chunk >> 3;               // b*32+c
    const int i0 = (chunk & 7) << 4;            // 16 i-rows per chunk
    const int il = lane & 15;                   // i_local (MFMA A-row / C-col)
    const int fg = lane >> 4;                   // k-subslice 0..3

    const float* xr0 = x + (long)plane * Hh * Ww + (long)(2 * (i0 + il)) * Ww;
    const float* xr1 = xr0 + Ww;
    const short* bl = Bg + lane * 8;            // per-lane fragment base

    f32x4 acc[2][8];
#pragma unroll
    for (int mi = 0; mi < 2; ++mi)
#pragma unroll
        for (int ni = 0; ni < 8; ++ni)
            acc[mi][ni] = (f32x4){0.f, 0.f, 0.f, 0.f};

    s16x8 b0[8], b1[8];                         // B double-buffer

    for (int jg = 0; jg < 4; ++jg) {
        const int cb = jg * 64 + fg * 16;       // x column base (16 floats)
        // issue ks=0 B-loads NOW; latency hides under the expansion below
        LOADB(b0, 0);
        u32x4 afr[2][9];                        // A-fragments [mi2][g]
#pragma unroll
        for (int p = 0; p < 4; ++p) {           // feature pairs
            f32x4 va = *(const f32x4*)(xr0 + cb + 4 * p);
            f32x4 vb = *(const f32x4*)(xr1 + cb + 4 * p);
            // Haar butterfly halves: kp=0 needs sums, kp=1 needs diffs
            float s01a = va[0] + va[1], d01a = va[0] - va[1];
            float s23a = vb[0] + vb[1], d23a = vb[0] - vb[1];
            float s01b = va[2] + va[3], d01b = va[2] - va[3];
            float s23b = vb[2] + vb[3], d23b = vb[2] - vb[3];
            float ua = kp ? d01a : s01a, wa = kp ? d23a : s23a;
            float ub = kp ? d01b : s01b, wb2 = kp ? d23b : s23b;
            float vkf[2][2];
            vkf[0][0] = 0.5f * (ua + wa); vkf[1][0] = 0.5f * (ua - wa);
            vkf[0][1] = 0.5f * (ub + wb2); vkf[1][1] = 0.5f * (ub - wb2);
#pragma unroll
            for (int mi = 0; mi < 2; ++mi) {
                float sl2[2]; unsigned Wf[2][4];
#pragma unroll
                for (int e = 0; e < 2; ++e) {
                    float v = vkf[mi][e];
                    float ex = __builtin_amdgcn_exp2f(-1.442695040888963f * v);
                    sl2[e] = v * __builtin_amdgcn_rcpf(1.0f + ex);      // silu
                    float xs = __builtin_fmaf(v, 2.5f, 5.5f);           // (v+2.2)*2.5
                    xs = fminf(fmaxf(xs, 0.0f), 10.999f);               // med3 clamp
                    float cf = floorf(xs);
                    float u = xs - cf;
                    int ci = (int)cf;                                   // 0..10
                    float u2 = u * u, u3 = u2 * u;
                    float wA = u3 * (1.f / 6.f);
                    float wB = (1.f + 3.f * u + 3.f * u2 - 3.f * u3) * (1.f / 6.f);
                    float wC = (4.f - 6.f * u2 + 3.f * u3) * (1.f / 6.f);
                    float um = 1.f - u;
                    float wD = um * um * um * (1.f / 6.f);
                    window128(wD, wC, wB, wA, ci, Wf[e]);
                }
                afr[mi][0][p] = pk_bf16(sl2[0], sl2[1]);
#pragma unroll
                for (int g = 1; g <= 8; ++g) {
                    int wq = (g - 1) >> 1;
                    unsigned sel = ((g - 1) & 1) ? 0x07060302u : 0x05040100u;
                    afr[mi][g][p] = __builtin_amdgcn_perm(Wf[1][wq], Wf[0][wq], sel);
                }
            }
        }
        // MFMA sweep, software-pipelined: loads for ks+1 issue before MFMA of ks
#pragma unroll
        for (int kh = 0; kh < 4; ++kh) {
            LOADB(b1, 2 * kh + 1);              // prefetch odd step
            MFMA_STEP(b0, 2 * kh);              // compute even step
            LOADB(b0, 2 * kh + 2);              // prefetch next even (kh=3 -> ks=8)
            MFMA_STEP(b1, 2 * kh + 1);          // compute odd step
        }
        MFMA_STEP(b0, 8);                       // final step
    }

    // epilogue: kcomp = kp*2+mi; z row = i0 + fg*4+rr, col = ni*16 + il
#pragma unroll
    for (int mi = 0; mi < 2; ++mi) {
        const int kcomp = kp * 2 + mi;
        long nb = ((long)(plane * 4 + kcomp) * H2 + i0) * NF;
#pragma unroll
        for (int rr = 0; rr < 4; ++rr) {
            long rowb = nb + (long)(fg * 4 + rr) * NF + il;
#pragma unroll
            for (int ni = 0; ni < 8; ++ni)
                z[rowb + ni * 16] = acc[mi][ni][rr];
        }
    }
}

// ---- K4: depthwise 5x5 conv + bias + inverse Haar -> out (final) ----
__global__ __launch_bounds__(256) void k_invconv(const float* __restrict__ x,
                                                 const float* __restrict__ cw,
                                                 const float* __restrict__ cb,
                                                 const float* __restrict__ z,
                                                 float* __restrict__ out) {
    __shared__ float sx[68][70];                // 19040 B, padded stride
    const int t = threadIdx.x;
    const int blk = blockIdx.x;
    const int tile = blk & 15;                  // 4x4 tiles of 64x64
    const int plane = blk >> 4;                 // b*32+c
    const int ty = tile >> 2, tx = tile & 3;
    const int c = plane & 31;
    const int Y0 = ty * 64, X0 = tx * 64;
    const float* xp = x + (long)plane * Hh * Ww;

    for (int idx = t; idx < 68 * 68; idx += 256) {
        int rr = idx / 68, cc2 = idx - rr * 68;
        int yy = Y0 - 2 + rr, xxp = X0 - 2 + cc2;
        float v = 0.f;
        if (yy >= 0 && yy < Hh && xxp >= 0 && xxp < Ww) v = xp[(long)yy * Ww + xxp];
        sx[rr][cc2] = v;
    }
    float w[25];
#pragma unroll
    for (int q = 0; q < 25; ++q) w[q] = cw[c * 25 + q];
    const float bias = cb[c];
    __syncthreads();

    const long zbase = (long)plane * 4 * H2 * W2;
    const long zplane = (long)H2 * W2;
#pragma unroll
    for (int p = 0; p < 4; ++p) {
        int q = t + p * 256;                    // quad id in 32x32
        int qy = q >> 5, qx = q & 31;
        int i = (Y0 >> 1) + qy, j = (X0 >> 1) + qx;
        long zi = zbase + (long)i * W2 + j;
        float z0 = z[zi];
        float z1 = z[zi + zplane];
        float z2 = z[zi + 2 * zplane];
        float z3 = z[zi + 3 * zplane];
        float y00 = 0.5f * (z0 + z1 + z2 + z3);
        float y01 = 0.5f * (z0 + z1 - z2 - z3);
        float y10 = 0.5f * (z0 - z1 + z2 - z3);
        float y11 = 0.5f * (z0 - z1 - z2 + z3);

        float vals[6][6];
#pragma unroll
        for (int rr = 0; rr < 6; ++rr)
#pragma unroll
            for (int c2 = 0; c2 < 3; ++c2) {
                float2 vv = *(const float2*)&sx[2 * qy + rr][2 * qx + 2 * c2];
                vals[rr][2 * c2] = vv.x; vals[rr][2 * c2 + 1] = vv.y;
            }
        float a00 = bias, a01 = bias, a10 = bias, a11 = bias;
#pragma unroll
        for (int ky = 0; ky < 5; ++ky)
#pragma unroll
            for (int kx = 0; kx < 5; ++kx) {
                float wvv = w[ky * 5 + kx];
                a00 += wvv * vals[ky][kx];
                a01 += wvv * vals[ky][kx + 1];
                a10 += wvv * vals[ky + 1][kx];
                a11 += wvv * vals[ky + 1][kx + 1];
            }
        float* op = out + (long)plane * Hh * Ww + (long)(Y0 + 2 * qy) * Ww + X0 + 2 * qx;
        *(float2*)op = make_float2(a00 + y00, a01 + y01);
        *(float2*)(op + Ww) = make_float2(a10 + y10, a11 + y11);
    }
}

extern "C" void kernel_launch(void* const* d_in, const int* in_sizes, int n_in,
                              void* d_out, int out_size, void* d_ws, size_t ws_size,
                              hipStream_t stream) {
    const float* x        = (const float*)d_in[0];
    const float* conv_w   = (const float*)d_in[1];
    const float* conv_b   = (const float*)d_in[2];
    const float* base_w   = (const float*)d_in[3];
    const float* spline_w = (const float*)d_in[4];
    const float* scaler   = (const float*)d_in[5];
    float* out = (float*)d_out;
    float* z   = (float*)d_ws;              // 65536 x 128 fp32 = 32 MiB
    short* Bg  = (short*)d_out;             // 288 KB staged in d_out (overwritten by k_invconv)

    // 1) fragment-order bf16 weights into d_out scratch
    k_wbuild<<<(NF * KTOT) / 256, 256, 0, stream>>>(base_w, spline_w, scaler, Bg);
    // 2) kcomp-split register-fragment KAN, B-pipelined -> z
    k_fused<<<1024, 128, 0, stream>>>(x, z, Bg);
    // 3) conv + inverse Haar -> out (fully overwrites d_out incl. Bg region)
    k_invconv<<<Bn * Cc * 16, 256, 0, stream>>>(x, conv_w, conv_b, z, out);
}